// Round 3
// baseline (151.448 us; speedup 1.0000x reference)
//
#include <hip/hip_runtime.h>
#include <math.h>

#define Bn 16
#define Tn 2048
#define En 128
#define Hn 128

typedef _Float16 f16;
typedef _Float16 f16x8 __attribute__((ext_vector_type(8)));
typedef _Float16 f16x4 __attribute__((ext_vector_type(4)));
typedef float    f32x4 __attribute__((ext_vector_type(4)));

#define MFMA16(a, b, c) __builtin_amdgcn_mfma_f32_16x16x32_f16(a, b, c, 0, 0, 0)

// ---------------------------------------------------------------------------
// Kernel 0: Wt[p][n][k] = W_p[k][n], f16.  Tiny (49K elems).
// ---------------------------------------------------------------------------
__global__ __launch_bounds__(256) void prep_wt(
    const float* __restrict__ Wq, const float* __restrict__ Wk,
    const float* __restrict__ Wv, f16* __restrict__ Wt)
{
    int id = blockIdx.x * 256 + threadIdx.x;      // 0 .. 49151
    int p = id >> 14;
    int rem = id & 16383;
    int nn = rem >> 7, kk = rem & 127;
    const float* W = (p == 0) ? Wq : (p == 1) ? Wk : Wv;
    Wt[id] = (f16)W[kk * Hn + nn];
}

// ---------------------------------------------------------------------------
// Kernel 1: Q/K/V projection via f16 MFMA.  Block = 64 x-rows, 4 waves.
// Outputs: Qf16 (pre-scaled 1/sqrt(H)) [b*T+t][h], Kf16 [b*T+t][h],
//          Vt f16 [b][h][t] (transposed through LDS for coalesced stores).
// Fragment maps (16x16x32): A/B: m|n=lane&15, k=(lane>>4)*8+j;
//                           D: col=lane&15, row=(lane>>4)*4+reg (m89).
// ---------------------------------------------------------------------------
__global__ __launch_bounds__(256) void qkv_proj(
    const float* __restrict__ x, const f16* __restrict__ Wt,
    const float* __restrict__ bq, const float* __restrict__ bk,
    const float* __restrict__ bv,
    f16* __restrict__ Qo, f16* __restrict__ Ko, f16* __restrict__ Vtp)
{
    __shared__ f16 xs[64][En + 8];    // stride 272B: b128 reads min-aliased
    __shared__ f16 wt[Hn][En + 8];    // current W^T tile [n][k]

    const int t = threadIdx.x;
    const long row0 = (long)blockIdx.x * 64;

    // Stage x fp32 -> f16 (2048 float4 loads, coalesced)
    {
        const float4* xg = (const float4*)(x + row0 * En);
        #pragma unroll
        for (int i = 0; i < 8; ++i) {
            int idx = t + i * 256;
            int r = idx >> 5, c4 = idx & 31;
            float4 v = xg[idx];
            f16x4 h = { (f16)v.x, (f16)v.y, (f16)v.z, (f16)v.w };
            *(f16x4*)&xs[r][c4 * 4] = h;
        }
    }
    __syncthreads();

    const int w = t >> 6, lane = t & 63;
    const int ln = lane & 15, hi = lane >> 4;

    // Hoist A-fragments (rows 16w+ln), reused across all 3 projections
    f16x8 xf[4];
    #pragma unroll
    for (int kss = 0; kss < 4; ++kss)
        xf[kss] = *(const f16x8*)&xs[w * 16 + ln][kss * 32 + hi * 8];

    const float* bias[3] = { bq, bk, bv };
    const int b  = (int)(row0 >> 11);      // row0 / Tn
    const int t0 = (int)(row0 & 2047);

    #pragma unroll
    for (int p = 0; p < 3; ++p) {
        __syncthreads();   // previous projection done with wt
        {
            const f16x8* wg = (const f16x8*)(Wt + p * En * Hn);
            #pragma unroll
            for (int i = 0; i < 8; ++i) {
                int idx = t + i * 256;
                *(f16x8*)&wt[idx >> 4][(idx & 15) * 8] = wg[idx];
            }
        }
        __syncthreads();

        f32x4 acc[8];
        #pragma unroll
        for (int i = 0; i < 8; ++i) acc[i] = (f32x4){0.f, 0.f, 0.f, 0.f};

        #pragma unroll
        for (int kss = 0; kss < 4; ++kss) {
            #pragma unroll
            for (int nt = 0; nt < 8; ++nt) {
                f16x8 bf = *(const f16x8*)&wt[nt * 16 + ln][kss * 32 + hi * 8];
                acc[nt] = MFMA16(xf[kss], bf, acc[nt]);
            }
        }

        if (p < 2) {
            const float scl = (p == 0) ? 0.08838834764831845f : 1.0f;
            f16* dst = (p == 0) ? Qo : Ko;
            #pragma unroll
            for (int nt = 0; nt < 8; ++nt) {
                int col = nt * 16 + ln;
                float bvv = bias[p][col];
                #pragma unroll
                for (int reg = 0; reg < 4; ++reg) {
                    int rr = w * 16 + hi * 4 + reg;
                    dst[(row0 + rr) * Hn + col] = (f16)((acc[nt][reg] + bvv) * scl);
                }
            }
        } else {
            // V: transpose through LDS (alias dead wt), coalesced store
            f16 (*vbuf)[72] = reinterpret_cast<f16(*)[72]>(&wt[0][0]);
            __syncthreads();   // all waves done reading wt
            #pragma unroll
            for (int nt = 0; nt < 8; ++nt) {
                int col = nt * 16 + ln;
                float bvv = bias[2][col];
                f16x4 hv;
                #pragma unroll
                for (int reg = 0; reg < 4; ++reg)
                    hv[reg] = (f16)(acc[nt][reg] + bvv);
                *(f16x4*)&vbuf[col][w * 16 + hi * 4] = hv;
            }
            __syncthreads();
            #pragma unroll
            for (int i = 0; i < 4; ++i) {
                int idx = t + i * 256;
                int h = idx >> 3, c = idx & 7;
                *(f16x8*)(Vtp + ((long)b * Hn + h) * Tn + t0 + c * 8) =
                    *(const f16x8*)&vbuf[h][c * 8];
            }
        }
    }
}

// ---------------------------------------------------------------------------
// Kernel 2: causal flash attention, f16 MFMA, fp32 accum/softmax.
// Block = 4 waves x 16 q-rows (QB=64), KB=64, double-buffered K/V with
// async-STAGE split (T14): one barrier per KV tile.
// Grid 512; qi remap pairs blocks n,n+256 (same CU) as (j,31-j): every CU
// gets exactly 33 KV-tiles.  Same-batch blocks share an XCD (bb = n&15).
// ---------------------------------------------------------------------------
__global__ __launch_bounds__(256, 2) void attn_fwd(
    const f16* __restrict__ Qf, const f16* __restrict__ Kf,
    const f16* __restrict__ Vt, float* __restrict__ Out)
{
    __shared__ f16 ksh[2][64][En + 8];     // [buf][key][h]   stride 272B
    __shared__ f16 vsh[2][Hn][64 + 8];     // [buf][h][key]   stride 144B
    __shared__ f16 psh[4][16][64 + 8];     // per-wave P [q][key]

    const int t = threadIdx.x;
    const int w = t >> 6, lane = t & 63;
    const int ln = lane & 15, hi = lane >> 4;

    const int n = blockIdx.x;
    const int s = n >> 8, r = n & 255;
    const int j = r >> 4, bb = r & 15;
    const int qi = s ? (31 - j) : j;       // LPT pairing
    const int q0 = qi * 64;
    const int nkt = qi + 1;
    const long qbase = ((long)bb * Tn + q0) * Hn;
    const long kbase = (long)bb * Tn * Hn;
    const long vbase = (long)bb * Hn * Tn;

    // Q fragments in registers (reused across all KV tiles)
    f16x8 qfr[4];
    #pragma unroll
    for (int kss = 0; kss < 4; ++kss)
        qfr[kss] = *(const f16x8*)(Qf + qbase + (long)(16 * w + ln) * Hn
                                   + kss * 32 + hi * 8);

    f32x4 oacc[8];
    #pragma unroll
    for (int i = 0; i < 8; ++i) oacc[i] = (f32x4){0.f, 0.f, 0.f, 0.f};
    float mrow[4], lrow[4];
    #pragma unroll
    for (int i = 0; i < 4; ++i) { mrow[i] = -INFINITY; lrow[i] = 0.f; }

    f16x8 kreg[4], vreg[4];
    // ---- prologue: stage tile 0 ----
    {
        const f16* Kg = Kf + kbase;
        const f16* Vg = Vt + vbase;
        #pragma unroll
        for (int i = 0; i < 4; ++i) {
            int idx = t + i * 256;
            kreg[i] = *(const f16x8*)(Kg + (long)(idx >> 4) * Hn + (idx & 15) * 8);
            vreg[i] = *(const f16x8*)(Vg + (long)(idx >> 3) * Tn + (idx & 7) * 8);
        }
        #pragma unroll
        for (int i = 0; i < 4; ++i) {
            int idx = t + i * 256;
            *(f16x8*)&ksh[0][idx >> 4][(idx & 15) * 8] = kreg[i];
            *(f16x8*)&vsh[0][idx >> 3][(idx & 7) * 8] = vreg[i];
        }
    }
    __syncthreads();

    int cur = 0;
    for (int kt = 0; kt < nkt; ++kt) {
        const int k0 = kt * 64;
        const bool pre = (kt + 1 < nkt);

        // ---- T14: issue next tile's global loads now; write to LDS later ----
        if (pre) {
            const f16* Kg = Kf + kbase + (long)(k0 + 64) * Hn;
            const f16* Vg = Vt + vbase + (k0 + 64);
            #pragma unroll
            for (int i = 0; i < 4; ++i) {
                int idx = t + i * 256;
                kreg[i] = *(const f16x8*)(Kg + (long)(idx >> 4) * Hn + (idx & 15) * 8);
                vreg[i] = *(const f16x8*)(Vg + (long)(idx >> 3) * Tn + (idx & 7) * 8);
            }
        }

        // ---- QK^T: wave's 16 q-rows x 64 keys ----
        f32x4 sacc[4];
        #pragma unroll
        for (int i = 0; i < 4; ++i) sacc[i] = (f32x4){0.f, 0.f, 0.f, 0.f};
        __builtin_amdgcn_s_setprio(1);
        #pragma unroll
        for (int kss = 0; kss < 4; ++kss) {
            #pragma unroll
            for (int nt = 0; nt < 4; ++nt) {
                f16x8 bf = *(const f16x8*)&ksh[cur][nt * 16 + ln][kss * 32 + hi * 8];
                sacc[nt] = MFMA16(qfr[kss], bf, sacc[nt]);
            }
        }
        __builtin_amdgcn_s_setprio(0);

        // ---- online softmax (lane's rows: q = q0+16w+hi*4+reg) ----
        const bool diag = (kt == nkt - 1);
        #pragma unroll
        for (int reg = 0; reg < 4; ++reg) {
            int gq = q0 + 16 * w + hi * 4 + reg;
            float s0 = sacc[0][reg], s1 = sacc[1][reg],
                  s2 = sacc[2][reg], s3 = sacc[3][reg];
            if (diag) {   // only the diagonal tile masks
                s0 = (k0 + ln      <= gq) ? s0 : -1e12f;
                s1 = (k0 + ln + 16 <= gq) ? s1 : -1e12f;
                s2 = (k0 + ln + 32 <= gq) ? s2 : -1e12f;
                s3 = (k0 + ln + 48 <= gq) ? s3 : -1e12f;
            }
            float mx = fmaxf(fmaxf(s0, s1), fmaxf(s2, s3));
            mx = fmaxf(mx, __shfl_xor(mx, 1));
            mx = fmaxf(mx, __shfl_xor(mx, 2));
            mx = fmaxf(mx, __shfl_xor(mx, 4));
            mx = fmaxf(mx, __shfl_xor(mx, 8));
            float mnew = fmaxf(mrow[reg], mx);
            float p0 = __expf(s0 - mnew), p1 = __expf(s1 - mnew);
            float p2 = __expf(s2 - mnew), p3 = __expf(s3 - mnew);
            float sm = p0 + p1 + p2 + p3;
            sm += __shfl_xor(sm, 1);
            sm += __shfl_xor(sm, 2);
            sm += __shfl_xor(sm, 4);
            sm += __shfl_xor(sm, 8);
            float f = __expf(mrow[reg] - mnew);   // first tile: exp(-inf)=0
            mrow[reg] = mnew;
            lrow[reg] = lrow[reg] * f + sm;
            #pragma unroll
            for (int nt2 = 0; nt2 < 8; ++nt2) oacc[nt2][reg] *= f;
            int qr = hi * 4 + reg;
            psh[w][qr][ln]      = (f16)p0;
            psh[w][qr][ln + 16] = (f16)p1;
            psh[w][qr][ln + 32] = (f16)p2;
            psh[w][qr][ln + 48] = (f16)p3;
        }
        // psh is wave-private: write->read ordered by in-wave lgkmcnt.

        // ---- PV: O += P (16x64) * V^T tile ----
        __builtin_amdgcn_s_setprio(1);
        #pragma unroll
        for (int kss = 0; kss < 2; ++kss) {
            f16x8 pa = *(const f16x8*)&psh[w][ln][kss * 32 + hi * 8];
            #pragma unroll
            for (int nt = 0; nt < 8; ++nt) {
                f16x8 vb = *(const f16x8*)&vsh[cur][nt * 16 + ln][kss * 32 + hi * 8];
                oacc[nt] = MFMA16(pa, vb, oacc[nt]);
            }
        }
        __builtin_amdgcn_s_setprio(0);

        // ---- write prefetched tile to alternate buffer; one barrier ----
        if (pre) {
            #pragma unroll
            for (int i = 0; i < 4; ++i) {
                int idx = t + i * 256;
                *(f16x8*)&ksh[cur ^ 1][idx >> 4][(idx & 15) * 8] = kreg[i];
                *(f16x8*)&vsh[cur ^ 1][idx >> 3][(idx & 7) * 8] = vreg[i];
            }
            __syncthreads();
            cur ^= 1;
        }
    }

    // ---- epilogue ----
    #pragma unroll
    for (int reg = 0; reg < 4; ++reg) {
        float inv = 1.0f / lrow[reg];
        long orow = qbase + (long)(16 * w + hi * 4 + reg) * Hn;
        #pragma unroll
        for (int nt = 0; nt < 8; ++nt)
            Out[orow + nt * 16 + ln] = oacc[nt][reg] * inv;
    }
}

// ---------------------------------------------------------------------------
extern "C" void kernel_launch(void* const* d_in, const int* in_sizes, int n_in,
                              void* d_out, int out_size, void* d_ws, size_t ws_size,
                              hipStream_t stream)
{
    const float* x  = (const float*)d_in[0];
    const float* Wq = (const float*)d_in[1];
    const float* bq = (const float*)d_in[2];
    const float* Wk = (const float*)d_in[3];
    const float* bk = (const float*)d_in[4];
    const float* Wv = (const float*)d_in[5];
    const float* bv = (const float*)d_in[6];

    // Workspace (f16): Q | K | V^T | Wt  — ~25.3 MB
    const size_t NE = (size_t)Bn * Tn * Hn;   // 4,194,304
    f16* Qf = (f16*)d_ws;
    f16* Kf = Qf + NE;
    f16* Vt = Kf + NE;
    f16* Wt = Vt + NE;

    prep_wt<<<dim3(192), dim3(256), 0, stream>>>(Wq, Wk, Wv, Wt);
    qkv_proj<<<dim3((Bn * Tn) / 64), dim3(256), 0, stream>>>(
        x, Wt, bq, bk, bv, Qf, Kf, Vt);
    attn_fwd<<<dim3(512), dim3(256), 0, stream>>>(Qf, Kf, Vt, (float*)d_out);
}

// Round 6
// 145.280 us; speedup vs baseline: 1.0425x; 1.0425x over previous
//
#include <hip/hip_runtime.h>
#include <math.h>

#define Bn 16
#define Tn 2048
#define En 128
#define Hn 128

typedef _Float16 f16;
typedef _Float16 f16x8 __attribute__((ext_vector_type(8)));
typedef _Float16 f16x4 __attribute__((ext_vector_type(4)));
typedef float    f32x4 __attribute__((ext_vector_type(4)));

#define MFMA16(a, b, c) __builtin_amdgcn_mfma_f32_16x16x32_f16(a, b, c, 0, 0, 0)

// ---------------------------------------------------------------------------
// Kernel 0: Wt[p][n][k] = W_p[k][n] f16, via LDS transpose (coalesced both
// sides).  One block per matrix.
// ---------------------------------------------------------------------------
__global__ __launch_bounds__(256) void prep_wt(
    const float* __restrict__ Wq, const float* __restrict__ Wk,
    const float* __restrict__ Wv, f16* __restrict__ Wt)
{
    __shared__ f16 lds[En][Hn + 8];       // [n][k], stride 272B
    const int t = threadIdx.x;
    const int p = blockIdx.x;
    const float* W = (p == 0) ? Wq : (p == 1) ? Wk : Wv;

    // coalesced float4 reads of W[k][n]; transposed scalar LDS writes
    #pragma unroll
    for (int i = 0; i < 16; ++i) {
        int idx = t + i * 256;            // 4096 float4
        int k = idx >> 5, n4 = idx & 31;
        float4 v = ((const float4*)W)[idx];
        #pragma unroll
        for (int j = 0; j < 4; ++j)
            lds[n4 * 4 + j][k] = (f16)(&v.x)[j];
    }
    __syncthreads();
    // coalesced f16x8 stores of Wt[n][k]
    #pragma unroll
    for (int i = 0; i < 8; ++i) {
        int idx = t + i * 256;            // 2048 chunks
        int n = idx >> 4, c = idx & 15;
        *(f16x8*)(Wt + p * En * Hn + n * Hn + c * 8) = *(const f16x8*)&lds[n][c * 8];
    }
}

// ---------------------------------------------------------------------------
// Kernel 1: Q/K/V projection via f16 MFMA.  Block = 64 x-rows, 4 waves.
// LDS 52.2 KB (xs 17.4 + wt 34.8) -> 2+ blocks/CU.  One W^T staged at a
// time; all outputs staged through LDS and stored as coalesced f16x8:
//   Q/K: [t][h] tile aliased on xs (x-fragments hoisted to regs first);
//   V:   [h][t] tile aliased on wt (dead after last MFMA).
// Q is pre-scaled by (1/sqrt(H))*log2(e): attention softmax runs in
// exp2-domain (saves the hidden mul in __expf; p-values identical).
// Fragment maps (16x16x32): A/B: m|n=lane&15, k=(lane>>4)*8+j;
//                           D: col=lane&15, row=(lane>>4)*4+reg (m89).
// ---------------------------------------------------------------------------
__global__ __launch_bounds__(256, 2) void qkv_proj(
    const float* __restrict__ x, const f16* __restrict__ Wt,
    const float* __restrict__ bq, const float* __restrict__ bk,
    const float* __restrict__ bv,
    f16* __restrict__ Qo, f16* __restrict__ Ko, f16* __restrict__ Vtp)
{
    __shared__ f16 xs[64][En + 8];        // 17408 B; doubles as Q/K out-tile
    __shared__ f16 wt[Hn][En + 8];        // 34816 B; doubles as V out-tile

    const int t = threadIdx.x;
    const long row0 = (long)blockIdx.x * 64;

    // Stage x fp32 -> f16 (coalesced float4 reads)
    {
        const float4* xg = (const float4*)(x + row0 * En);
        #pragma unroll
        for (int i = 0; i < 8; ++i) {
            int idx = t + i * 256;
            int r = idx >> 5, c4 = idx & 31;
            float4 v = xg[idx];
            f16x4 h = { (f16)v.x, (f16)v.y, (f16)v.z, (f16)v.w };
            *(f16x4*)&xs[r][c4 * 4] = h;
        }
    }
    // Stage W^T[0]
    {
        const f16x8* wg = (const f16x8*)Wt;
        #pragma unroll
        for (int i = 0; i < 8; ++i) {
            int idx = t + i * 256;
            *(f16x8*)&wt[idx >> 4][(idx & 15) * 8] = wg[idx];
        }
    }
    __syncthreads();

    const int w = t >> 6, lane = t & 63;
    const int ln = lane & 15, hi = lane >> 4;

    // Hoist A-fragments (rows 16w+ln); xs is then free for output staging
    f16x8 xf[4];
    #pragma unroll
    for (int kss = 0; kss < 4; ++kss)
        xf[kss] = *(const f16x8*)&xs[w * 16 + ln][kss * 32 + hi * 8];

    const float* bias[3] = { bq, bk, bv };
    const int b  = (int)(row0 >> 11);
    const int t0 = (int)(row0 & 2047);

    #pragma unroll
    for (int p = 0; p < 3; ++p) {
        f32x4 acc[8];
        #pragma unroll
        for (int i = 0; i < 8; ++i) acc[i] = (f32x4){0.f, 0.f, 0.f, 0.f};

        #pragma unroll
        for (int kss = 0; kss < 4; ++kss) {
            #pragma unroll
            for (int nt = 0; nt < 8; ++nt) {
                f16x8 bf = *(const f16x8*)&wt[nt * 16 + ln][kss * 32 + hi * 8];
                acc[nt] = MFMA16(xf[kss], bf, acc[nt]);
            }
        }
        __syncthreads();               // (A) all MFMA reads of wt/xs complete

        if (p < 2) {
            // stage next W^T while output staging proceeds
            const f16x8* wg = (const f16x8*)(Wt + (p + 1) * En * Hn);
            #pragma unroll
            for (int i = 0; i < 8; ++i) {
                int idx = t + i * 256;
                *(f16x8*)&wt[idx >> 4][(idx & 15) * 8] = wg[idx];
            }
            // D-frags (+bias, Q-scale incl. log2e) -> xs as [t][h]
            const float scl = (p == 0)
                ? 0.08838834764831845f * 1.4426950408889634f : 1.0f;
            #pragma unroll
            for (int nt = 0; nt < 8; ++nt) {
                int col = nt * 16 + ln;
                float bvv = bias[p][col];
                #pragma unroll
                for (int reg = 0; reg < 4; ++reg)
                    xs[w * 16 + hi * 4 + reg][col] =
                        (f16)((acc[nt][reg] + bvv) * scl);
            }
            __syncthreads();           // (B) out-tile + next W ready
            f16* dst = (p == 0) ? Qo : Ko;
            #pragma unroll
            for (int i = 0; i < 4; ++i) {
                int idx = t + i * 256;
                int r = idx >> 4, c = idx & 15;
                *(f16x8*)(dst + (row0 + r) * Hn + c * 8) = *(const f16x8*)&xs[r][c * 8];
            }
        } else {
            // V: transpose through wt-alias [h=128][t=64+8pad]
            f16 (*vbuf)[72] = reinterpret_cast<f16(*)[72]>(&wt[0][0]);
            #pragma unroll
            for (int nt = 0; nt < 8; ++nt) {
                int col = nt * 16 + ln;
                float bvv = bias[2][col];
                f16x4 hv;
                #pragma unroll
                for (int reg = 0; reg < 4; ++reg)
                    hv[reg] = (f16)(acc[nt][reg] + bvv);
                *(f16x4*)&vbuf[col][w * 16 + hi * 4] = hv;
            }
            __syncthreads();           // (B)
            #pragma unroll
            for (int i = 0; i < 4; ++i) {
                int idx = t + i * 256;
                int h = idx >> 3, c = idx & 7;
                *(f16x8*)(Vtp + ((long)b * Hn + h) * Tn + t0 + c * 8) =
                    *(const f16x8*)&vbuf[h][c * 8];
            }
        }
    }
}

// ---------------------------------------------------------------------------
// Kernel 2: causal flash attention, f16 MFMA, fp32 accum/softmax (exp2
// domain; Q carries the log2e factor).  Block = 4 waves x 16 q-rows
// (QB=64), KB=64, single-buffered 45KB LDS (2+ blocks/CU) + T14
// reg-prefetch (loads issued pre-QK, LDS write post-barrier).
// Defer-max (THR=8 nats = 11.54 in log2 units): lane-local trigger (no
// shuffles); l lane-partial, reduced once in epilogue.
// ---------------------------------------------------------------------------
__global__ __launch_bounds__(256, 2) void attn_fwd(
    const f16* __restrict__ Qf, const f16* __restrict__ Kf,
    const f16* __restrict__ Vt, float* __restrict__ Out)
{
    __shared__ f16 ksh[64][En + 8];        // 17408 B  [key][h]
    __shared__ f16 vsh[Hn][64 + 8];        // 18432 B  [h][key]
    __shared__ f16 psh[4][16][64 + 8];     //  9216 B  per-wave P [q][key]

    const int t = threadIdx.x;
    const int w = t >> 6, lane = t & 63;
    const int ln = lane & 15, hi = lane >> 4;

    const int n = blockIdx.x;
    const int s = n >> 8, r = n & 255;
    const int j = r >> 4, bb = r & 15;
    const int qi = s ? (31 - j) : j;       // LPT pairing
    const int q0 = qi * 64;
    const int nkt = qi + 1;
    const long qbase = ((long)bb * Tn + q0) * Hn;
    const long kbase = (long)bb * Tn * Hn;
    const long vbase = (long)bb * Hn * Tn;

    f16x8 qfr[4];
    #pragma unroll
    for (int kss = 0; kss < 4; ++kss)
        qfr[kss] = *(const f16x8*)(Qf + qbase + (long)(16 * w + ln) * Hn
                                   + kss * 32 + hi * 8);

    f32x4 oacc[8];
    #pragma unroll
    for (int i = 0; i < 8; ++i) oacc[i] = (f32x4){0.f, 0.f, 0.f, 0.f};
    float mrow[4], lpart[4];
    #pragma unroll
    for (int i = 0; i < 4; ++i) { mrow[i] = -INFINITY; lpart[i] = 0.f; }

    {
        const f16* Kg = Kf + kbase;
        const f16* Vg = Vt + vbase;
        #pragma unroll
        for (int i = 0; i < 4; ++i) {
            int idx = t + i * 256;
            *(f16x8*)&ksh[idx >> 4][(idx & 15) * 8] =
                *(const f16x8*)(Kg + (long)(idx >> 4) * Hn + (idx & 15) * 8);
            *(f16x8*)&vsh[idx >> 3][(idx & 7) * 8] =
                *(const f16x8*)(Vg + (long)(idx >> 3) * Tn + (idx & 7) * 8);
        }
    }
    __syncthreads();

    for (int kt = 0; kt < nkt; ++kt) {
        const int k0 = kt * 64;
        const bool pre = (kt + 1 < nkt);

        // T14: issue next tile's global loads now; LDS-write after barrier
        f16x8 kreg[4], vreg[4];
        if (pre) {
            const f16* Kg = Kf + kbase + (long)(k0 + 64) * Hn;
            const f16* Vg = Vt + vbase + (k0 + 64);
            #pragma unroll
            for (int i = 0; i < 4; ++i) {
                int idx = t + i * 256;
                kreg[i] = *(const f16x8*)(Kg + (long)(idx >> 4) * Hn + (idx & 15) * 8);
                vreg[i] = *(const f16x8*)(Vg + (long)(idx >> 3) * Tn + (idx & 7) * 8);
            }
        }

        // ---- QK^T (log2-domain logits) ----
        f32x4 sacc[4];
        #pragma unroll
        for (int i = 0; i < 4; ++i) sacc[i] = (f32x4){0.f, 0.f, 0.f, 0.f};
        __builtin_amdgcn_s_setprio(1);
        #pragma unroll
        for (int kss = 0; kss < 4; ++kss) {
            #pragma unroll
            for (int nt = 0; nt < 4; ++nt) {
                f16x8 bf = *(const f16x8*)&ksh[nt * 16 + ln][kss * 32 + hi * 8];
                sacc[nt] = MFMA16(qfr[kss], bf, sacc[nt]);
            }
        }
        __builtin_amdgcn_s_setprio(0);

        // ---- mask ----
        const bool diag = (kt == nkt - 1);
        float sv[4][4];
        #pragma unroll
        for (int reg = 0; reg < 4; ++reg) {
            int gq = q0 + 16 * w + hi * 4 + reg;
            #pragma unroll
            for (int nt = 0; nt < 4; ++nt) {
                float v = sacc[nt][reg];
                if (diag) v = (k0 + nt * 16 + ln <= gq) ? v : -1e12f;
                sv[reg][nt] = v;
            }
        }

        // ---- defer-max trigger: lane-local, no shuffles ----
        float worst = -INFINITY;
        #pragma unroll
        for (int reg = 0; reg < 4; ++reg) {
            float pm = fmaxf(fmaxf(sv[reg][0], sv[reg][1]),
                             fmaxf(sv[reg][2], sv[reg][3]));
            worst = fmaxf(worst, pm - mrow[reg]);
        }
        if (__any(worst > 11.5415603f)) {   // 8 nats; ~once per block
            #pragma unroll
            for (int reg = 0; reg < 4; ++reg) {
                float mx = fmaxf(fmaxf(sv[reg][0], sv[reg][1]),
                                 fmaxf(sv[reg][2], sv[reg][3]));
                mx = fmaxf(mx, __shfl_xor(mx, 1));
                mx = fmaxf(mx, __shfl_xor(mx, 2));
                mx = fmaxf(mx, __shfl_xor(mx, 4));
                mx = fmaxf(mx, __shfl_xor(mx, 8));
                float mnew = fmaxf(mrow[reg], mx);
                float f = exp2f(mrow[reg] - mnew);   // -inf -> 0 on tile 0
                mrow[reg] = mnew;
                lpart[reg] *= f;
                #pragma unroll
                for (int nt2 = 0; nt2 < 8; ++nt2) oacc[nt2][reg] *= f;
            }
        }

        // ---- P = 2^(s-m) = e^(logit-m_e) (≤ e^8), lane-partial l ----
        #pragma unroll
        for (int reg = 0; reg < 4; ++reg) {
            float p0 = exp2f(sv[reg][0] - mrow[reg]);
            float p1 = exp2f(sv[reg][1] - mrow[reg]);
            float p2 = exp2f(sv[reg][2] - mrow[reg]);
            float p3 = exp2f(sv[reg][3] - mrow[reg]);
            lpart[reg] += (p0 + p1) + (p2 + p3);
            int qr = hi * 4 + reg;
            psh[w][qr][ln]      = (f16)p0;
            psh[w][qr][ln + 16] = (f16)p1;
            psh[w][qr][ln + 32] = (f16)p2;
            psh[w][qr][ln + 48] = (f16)p3;
        }
        // psh wave-private: in-wave ds write->read ordering (HW-validated R3)

        // ---- PV ----
        __builtin_amdgcn_s_setprio(1);
        #pragma unroll
        for (int kss = 0; kss < 2; ++kss) {
            f16x8 pa = *(const f16x8*)&psh[w][ln][kss * 32 + hi * 8];
            #pragma unroll
            for (int nt = 0; nt < 8; ++nt) {
                f16x8 vb = *(const f16x8*)&vsh[nt * 16 + ln][kss * 32 + hi * 8];
                oacc[nt] = MFMA16(pa, vb, oacc[nt]);
            }
        }
        __builtin_amdgcn_s_setprio(0);

        __syncthreads();
        if (pre) {
            #pragma unroll
            for (int i = 0; i < 4; ++i) {
                int idx = t + i * 256;
                *(f16x8*)&ksh[idx >> 4][(idx & 15) * 8] = kreg[i];
                *(f16x8*)&vsh[idx >> 3][(idx & 7) * 8] = vreg[i];
            }
            __syncthreads();
        }
    }

    // ---- epilogue: reduce lane-partial l, normalize, store ----
    #pragma unroll
    for (int reg = 0; reg < 4; ++reg) {
        float lr = lpart[reg];
        lr += __shfl_xor(lr, 1);
        lr += __shfl_xor(lr, 2);
        lr += __shfl_xor(lr, 4);
        lr += __shfl_xor(lr, 8);
        float inv = 1.0f / lr;
        long orow = qbase + (long)(16 * w + hi * 4 + reg) * Hn;
        #pragma unroll
        for (int nt = 0; nt < 8; ++nt)
            Out[orow + nt * 16 + ln] = oacc[nt][reg] * inv;
    }
}

// ---------------------------------------------------------------------------
extern "C" void kernel_launch(void* const* d_in, const int* in_sizes, int n_in,
                              void* d_out, int out_size, void* d_ws, size_t ws_size,
                              hipStream_t stream)
{
    const float* x  = (const float*)d_in[0];
    const float* Wq = (const float*)d_in[1];
    const float* bq = (const float*)d_in[2];
    const float* Wk = (const float*)d_in[3];
    const float* bk = (const float*)d_in[4];
    const float* Wv = (const float*)d_in[5];
    const float* bv = (const float*)d_in[6];

    // Workspace (f16): Q | K | V^T | Wt  — ~25.3 MB
    const size_t NE = (size_t)Bn * Tn * Hn;   // 4,194,304
    f16* Qf = (f16*)d_ws;
    f16* Kf = Qf + NE;
    f16* Vt = Kf + NE;
    f16* Wt = Vt + NE;

    prep_wt<<<dim3(3), dim3(256), 0, stream>>>(Wq, Wk, Wv, Wt);
    qkv_proj<<<dim3((Bn * Tn) / 64), dim3(256), 0, stream>>>(
        x, Wt, bq, bk, bv, Qf, Kf, Vt);
    attn_fwd<<<dim3(512), dim3(256), 0, stream>>>(Qf, Kf, Vt, (float*)d_out);
}